// Round 1
// baseline (2246.815 us; speedup 1.0000x reference)
//
#include <hip/hip_runtime.h>
#include <math.h>

#define BB 64
#define NN 8192
#define LL 64
#define KK 20
#define TILE 128
#define ZS 68     // z_s row stride (floats): 272 B, 16B-aligned, bank-balanced
#define PS 132    // pt row stride (floats): 528 B, 16B-aligned

// ---------------------------------------------------------------------------
// ws layout (floats):
//   IA   : [64*64]            @ 0
//   M    : [64*64]            @ 4096
//   bias : [B*K]              @ 8192
//   nk   : [B*K]              @ 9472
//   macc : [B*K*L]            @ 10752
// total 92672 floats = 370,688 B
// ---------------------------------------------------------------------------

// Compute IA = I - A and M = inv(I + IA @ IA^T) via Gauss-Jordan (SPD, no
// pivoting needed: S = I + IA IA^T has eigenvalues >= 1).
__global__ __launch_bounds__(256) void k_setup(const float* __restrict__ A,
                                               float* __restrict__ IA,
                                               float* __restrict__ M) {
    __shared__ __align__(16) float ia[64][64];
    __shared__ __align__(16) float aug[64][130];
    int t = threadIdx.x;
    for (int i = t; i < 4096; i += 256) {
        int r = i >> 6, c = i & 63;
        float v = (r == c ? 1.0f : 0.0f) - A[i];
        ia[r][c] = v;
        IA[i] = v;
    }
    __syncthreads();
    for (int i = t; i < 4096; i += 256) {
        int r = i >> 6, c = i & 63;
        float s = (r == c) ? 1.0f : 0.0f;
        for (int l = 0; l < 64; ++l) s += ia[r][l] * ia[c][l];
        aug[r][c] = s;
        aug[r][64 + c] = (r == c) ? 1.0f : 0.0f;
    }
    __syncthreads();
    int r = t >> 2;              // 4 threads per row
    int c0 = (t & 3) * 32;       // 32 cols each -> covers 128 cols
    for (int k = 0; k < 64; ++k) {
        float pivinv = 1.0f / aug[k][k];
        float f = aug[r][k] * pivinv;   // read before any write this iter
        __syncthreads();
        if (r != k) {
            #pragma unroll 8
            for (int c = c0; c < c0 + 32; ++c) aug[r][c] -= f * aug[k][c];
        }
        __syncthreads();
        if (r == k) {
            #pragma unroll 8
            for (int c = c0; c < c0 + 32; ++c) aug[r][c] *= pivinv;
        }
        __syncthreads();
    }
    for (int i = t; i < 4096; i += 256) {
        int rr = i >> 6, c = i & 63;
        M[i] = aug[rr][64 + c];
    }
}

// Per (b,k): mean = z[b, idx, :] @ M ; write bias; zero accumulators.
__global__ __launch_bounds__(64) void k_init(const float* __restrict__ z,
                                             const int* __restrict__ idxs,
                                             const float* __restrict__ M,
                                             const float* __restrict__ IA,
                                             float* __restrict__ out_mean,
                                             float* __restrict__ bias,
                                             float* __restrict__ nk,
                                             float* __restrict__ macc) {
    int k = blockIdx.x, b = blockIdx.y;
    int l = threadIdx.x;
    int bk = b * KK + k;
    __shared__ float srow[64];
    __shared__ float smean[64];
    int idx = idxs[bk];
    srow[l] = z[((size_t)b * NN + idx) * LL + l];
    __syncthreads();
    float nm = 0.f;
    #pragma unroll 8
    for (int m = 0; m < 64; ++m) nm += srow[m] * M[m * 64 + l];
    out_mean[(size_t)bk * LL + l] = nm;
    smean[l] = nm;
    __syncthreads();
    float cm = 0.f;
    #pragma unroll 8
    for (int m = 0; m < 64; ++m) cm += smean[m] * IA[m * 64 + l];
    float sqm = nm * nm;
    float sqc = cm * cm;
    for (int off = 32; off > 0; off >>= 1) {
        sqm += __shfl_down(sqm, off);
        sqc += __shfl_down(sqc, off);
    }
    if (l == 0) {
        bias[bk] = logf(1.0f / KK) - 0.5f * (sqm + sqc);
        nk[bk] = 0.f;
    }
    macc[(size_t)bk * LL + l] = 0.f;
}

// Fused EM pass: logits -> softmax -> accumulate (Nk, post^T z) with atomics.
__global__ __launch_bounds__(256) void k_empass(const float* __restrict__ z,
                                                const float* __restrict__ mean,
                                                const float* __restrict__ bias,
                                                float* __restrict__ nk,
                                                float* __restrict__ macc) {
    __shared__ __align__(16) float z_s[TILE][ZS];
    __shared__ __align__(16) float mean_s[KK][ZS];
    __shared__ __align__(16) float pt[KK][PS];
    __shared__ float bias_s[KK];
    int t = threadIdx.x;
    int lane = t & 63;
    int q = t >> 6;             // wave id 0..3, owns k = q*5 .. q*5+4
    int b = blockIdx.y;
    int row0 = blockIdx.x * TILE;

    for (int i = t; i < KK * LL; i += 256) {
        int k = i >> 6, l = i & 63;
        mean_s[k][l] = mean[((size_t)b * KK + k) * LL + l];
    }
    if (t < KK) bias_s[t] = bias[b * KK + t];
    const float4* zg = (const float4*)(z + ((size_t)b * NN + row0) * LL);
    for (int i = t; i < TILE * 16; i += 256) {
        int r = i >> 4, c = i & 15;
        float4 v = zg[i];
        *(float4*)&z_s[r][c * 4] = v;
    }
    __syncthreads();

    // ---- cross phase: rows (lane, lane+64), k-set q*5..q*5+4 ----
    float acc0[5], acc1[5];
    #pragma unroll
    for (int i = 0; i < 5; ++i) { acc0[i] = bias_s[q * 5 + i]; acc1[i] = acc0[i]; }
    #pragma unroll
    for (int lc = 0; lc < 64; lc += 8) {
        float4 a0 = *(const float4*)&z_s[lane][lc];
        float4 a1 = *(const float4*)&z_s[lane][lc + 4];
        float4 b0 = *(const float4*)&z_s[lane + 64][lc];
        float4 b1 = *(const float4*)&z_s[lane + 64][lc + 4];
        #pragma unroll
        for (int i = 0; i < 5; ++i) {
            int kk = q * 5 + i;
            float4 m0 = *(const float4*)&mean_s[kk][lc];
            float4 m1 = *(const float4*)&mean_s[kk][lc + 4];
            acc0[i] += a0.x * m0.x + a0.y * m0.y + a0.z * m0.z + a0.w * m0.w
                     + a1.x * m1.x + a1.y * m1.y + a1.z * m1.z + a1.w * m1.w;
            acc1[i] += b0.x * m0.x + b0.y * m0.y + b0.z * m0.z + b0.w * m0.w
                     + b1.x * m1.x + b1.y * m1.y + b1.z * m1.z + b1.w * m1.w;
        }
    }
    #pragma unroll
    for (int i = 0; i < 5; ++i) {
        pt[q * 5 + i][lane] = acc0[i];
        pt[q * 5 + i][lane + 64] = acc1[i];
    }
    __syncthreads();

    // ---- softmax: thread t < 128 handles row t ----
    if (t < TILE) {
        float mx = pt[0][t];
        #pragma unroll
        for (int k = 1; k < KK; ++k) mx = fmaxf(mx, pt[k][t]);
        float e[KK];
        float s = 0.f;
        #pragma unroll
        for (int k = 0; k < KK; ++k) { e[k] = __expf(pt[k][t] - mx); s += e[k]; }
        float inv = 1.0f / s;
        #pragma unroll
        for (int k = 0; k < KK; ++k) pt[k][t] = e[k] * inv;
    }
    __syncthreads();

    // ---- accumulate: wave q owns rows q*32 .. q*32+31, lane = column ----
    float pacc[KK];
    float nkp[KK];
    #pragma unroll
    for (int k = 0; k < KK; ++k) { pacc[k] = 0.f; nkp[k] = 0.f; }
    int rbase = q * 32;
    for (int r = rbase; r < rbase + 32; r += 4) {
        float zv0 = z_s[r][lane];
        float zv1 = z_s[r + 1][lane];
        float zv2 = z_s[r + 2][lane];
        float zv3 = z_s[r + 3][lane];
        #pragma unroll
        for (int k = 0; k < KK; ++k) {
            float4 p = *(const float4*)&pt[k][r];
            pacc[k] += p.x * zv0 + p.y * zv1 + p.z * zv2 + p.w * zv3;
            nkp[k] += (p.x + p.y) + (p.z + p.w);
        }
    }
    #pragma unroll
    for (int k = 0; k < KK; ++k) {
        atomicAdd(&macc[((size_t)b * KK + k) * LL + lane], pacc[k]);
    }
    if (lane == 0) {
        #pragma unroll
        for (int k = 0; k < KK; ++k) atomicAdd(&nk[b * KK + k], nkp[k]);
    }
}

// Per (b,k): pi = Nk/N, mean = (macc/Nk) @ M, bias for next iter, re-zero acc.
__global__ __launch_bounds__(64) void k_final(const float* __restrict__ Mm,
                                              const float* __restrict__ IA,
                                              float* __restrict__ nk,
                                              float* __restrict__ macc,
                                              float* __restrict__ bias,
                                              float* __restrict__ out_pi,
                                              float* __restrict__ out_mean,
                                              float* __restrict__ out_trace) {
    int k = blockIdx.x, b = blockIdx.y;
    int l = threadIdx.x;
    int bk = b * KK + k;
    __shared__ float sraw[64];
    __shared__ float smean[64];
    float Nk = nk[bk];
    if (Nk == 0.f) Nk = 1e-22f;
    float pi = Nk / (float)NN;
    float raw = macc[(size_t)bk * LL + l] / Nk;
    sraw[l] = raw;
    __syncthreads();
    float nm = 0.f;
    #pragma unroll 8
    for (int m = 0; m < 64; ++m) nm += sraw[m] * Mm[m * 64 + l];
    out_mean[(size_t)bk * LL + l] = nm;
    smean[l] = nm;
    __syncthreads();
    float cm = 0.f;
    #pragma unroll 8
    for (int m = 0; m < 64; ++m) cm += smean[m] * IA[m * 64 + l];
    float sqm = nm * nm;
    float sqc = cm * cm;
    for (int off = 32; off > 0; off >>= 1) {
        sqm += __shfl_down(sqm, off);
        sqc += __shfl_down(sqc, off);
    }
    if (l == 0) {
        bias[bk] = logf(pi) - 0.5f * (sqm + sqc);
        out_pi[bk] = pi;
        out_trace[bk] = 1.0f;
        nk[bk] = 0.f;
    }
    macc[(size_t)bk * LL + l] = 0.f;
}

extern "C" void kernel_launch(void* const* d_in, const int* in_sizes, int n_in,
                              void* d_out, int out_size, void* d_ws, size_t ws_size,
                              hipStream_t stream) {
    const float* z = (const float*)d_in[0];
    const float* A = (const float*)d_in[1];
    const int* idxs = (const int*)d_in[2];

    float* out_pi = (float*)d_out;
    float* out_mean = out_pi + BB * KK;
    float* out_trace = out_mean + (size_t)BB * KK * LL;

    float* ws = (float*)d_ws;
    float* IA = ws;
    float* M = ws + 4096;
    float* bias = ws + 8192;
    float* nk = ws + 9472;
    float* macc = ws + 10752;

    k_setup<<<1, 256, 0, stream>>>(A, IA, M);
    k_init<<<dim3(KK, BB), 64, 0, stream>>>(z, idxs, M, IA, out_mean, bias, nk, macc);
    for (int it = 0; it < 5; ++it) {
        k_empass<<<dim3(NN / TILE, BB), 256, 0, stream>>>(z, out_mean, bias, nk, macc);
        k_final<<<dim3(KK, BB), 64, 0, stream>>>(M, IA, nk, macc, bias, out_pi, out_mean, out_trace);
    }
}